// Round 39
// baseline (159.747 us; speedup 1.0000x reference)
//
#include <hip/hip_runtime.h>

typedef unsigned short u16;
typedef unsigned int u32;
typedef __attribute__((ext_vector_type(8))) short short8;
typedef __attribute__((ext_vector_type(4))) float f32x4;

#define H_ 16
#define L_ 2048
#define D_ 64
#define HID_ 1024

__device__ __forceinline__ u16 f2bf(float f) {
  union { float f; u32 u; } v; v.f = f;
  u32 r = v.u + 0x7FFFu + ((v.u >> 16) & 1u);
  return (u16)(r >> 16);
}

// async global->LDS, 16B per lane
__device__ __forceinline__ void gl16(const u16* g, u16* l) {
  __builtin_amdgcn_global_load_lds(
      (const __attribute__((address_space(1))) void*)g,
      (__attribute__((address_space(3))) void*)l, 16, 0, 0);
}

// ---------------- merged prep kernel: cvt (0..2047) | transpose4 (2048..6143) | rope (6144..6399) ----------------

__global__ __launch_bounds__(256) void prep_k(
    const float* __restrict__ x, u16* __restrict__ xbf,
    const float* __restrict__ Wq, const float* __restrict__ Wk,
    const float* __restrict__ Wv, const float* __restrict__ Wo,
    u16* __restrict__ dWq, u16* __restrict__ dWk,
    u16* __restrict__ dWv, u16* __restrict__ dWo,
    const int* __restrict__ pos, float2* __restrict__ tab)
{
  __shared__ float t[32][33];
  int blk = blockIdx.x;
  if (blk < 2048) {
    // ---- cvt: x f32 -> xbf bf16 (4M elements) ----
    int i = (blk * 256 + threadIdx.x) * 8;
    float4 a = *(const float4*)(x + i);
    float4 b = *(const float4*)(x + i + 4);
    u16 r[8] = { f2bf(a.x), f2bf(a.y), f2bf(a.z), f2bf(a.w),
                 f2bf(b.x), f2bf(b.y), f2bf(b.z), f2bf(b.w) };
    *(uint4*)(xbf + i) = *(const uint4*)r;
  } else if (blk < 6144) {
    // ---- transpose: W [K][N] f32 -> Wt [N][K] bf16 (4 weights) ----
    int bb = blk - 2048;
    int w = bb >> 10;
    const float* in = (w == 0) ? Wq : (w == 1) ? Wk : (w == 2) ? Wv : Wo;
    u16* out = (w == 0) ? dWq : (w == 1) ? dWk : (w == 2) ? dWv : dWo;
    int bx = bb & 31, by = (bb >> 5) & 31;
    int c = threadIdx.x & 31, r0 = threadIdx.x >> 5;
#pragma unroll
    for (int p = 0; p < 4; ++p) {
      int r = r0 + p * 8;
      t[r][c] = in[(size_t)(by * 32 + r) * 1024 + bx * 32 + c];
    }
    __syncthreads();
#pragma unroll
    for (int p = 0; p < 4; ++p) {
      int r = r0 + p * 8;
      out[(size_t)(bx * 32 + r) * 1024 + by * 32 + c] = f2bf(t[c][r]);
    }
  } else {
    // ---- rope table: tab[l][i] = (cos, sin)(pos[l] * base^(-2i/64)) ----
    int gid = (blk - 6144) * 256 + threadIdx.x;
    int l = gid >> 5, i = gid & 31;
    float p = (float)pos[l];
    float inv = expf(-((float)(2 * i) / 64.0f) * logf(10000.0f));
    float th = p * inv;
    tab[gid] = make_float2(cosf(th), sinf(th));
  }
}

// ---------------- fused QKV GEMM v26: 128x192 tiles, 64x96 wave tiles ----------------
// 2x2 wave grid: per kk-half each wave reads 4 A + 6 B fragments for 24 MFMA
// (0.417 reads/MFMA vs 0.583 at 32x192) -> LDS-read pipe load -29%.
// Middle head straddles the wave-column boundary; its RoPE pair is exchanged
// through the retired As buffer in the epilogue (partner wave, same lane, same rows).
// V epilogue: chunk-tiled + kv-permuted slotpos (zero-shuffle PV in attn).

__global__ __launch_bounds__(256) void qkv_gemm_k(
    const u16* __restrict__ A, const u16* __restrict__ Bt,
    u16* __restrict__ Qo, u16* __restrict__ Ko, u16* __restrict__ Vo,
    const float2* __restrict__ rope)
{
  const int K = 1024;
  __shared__ alignas(16) u16 As[2][8192];    // 128 x 64
  __shared__ alignas(16) u16 Bs[2][12288];   // 192 x 64
  int tid = threadIdx.x;
  int orig = blockIdx.x;               // 0..511
  int xcd = orig & 7, idx = orig >> 3; // 0..63
  int px = xcd & 1, py = xcd >> 1;     // 2 x 4 XCD patch grid
  int tn = px * 8 + (idx & 7);         // 0..15
  int tm = py * 8 + (idx >> 3);        // 0..31
  int m0 = tm * 128, n0 = tn * 192;
  // staging source (pre-swizzled): thread t, pass s -> row s*32+(t>>3), block B
  int prow = tid >> 3;
  int pB = (tid & 7) ^ (prow & 7);
  const u16* gA0 = A + (size_t)(m0 + prow) * K + pB * 8;
  const u16* gB0 = Bt + (size_t)(n0 + prow) * K + pB * 8;
  int wid = tid >> 6, lane = tid & 63, ln = lane & 15, kg = lane >> 4;
  int wr = wid >> 1, wc = wid & 1;
  int wm = wr * 64, wn2 = wc * 96;     // wave tile origin
  f32x4 acc[4][6] = {};
  // swizzled read offsets: row r, k-half kk, block (kk*4+kg)^(r&7)
  int sw0 = (kg ^ (ln & 7)) * 8;
  int sw1 = ((4 + kg) ^ (ln & 7)) * 8;

  auto stage = [&](int kt, int buf) {
#pragma unroll
    for (int s = 0; s < 4; ++s)
      gl16(gA0 + (size_t)s * 32 * K + kt * 64, &As[buf][s * 2048 + tid * 8]);
#pragma unroll
    for (int s = 0; s < 6; ++s)
      gl16(gB0 + (size_t)s * 32 * K + kt * 64, &Bs[buf][s * 2048 + tid * 8]);
  };

  stage(0, 0);
  int cur = 0;
  for (int kt = 0; kt < 16; ++kt) {
    __builtin_amdgcn_s_barrier();
    if (kt + 1 < 16) {
      stage(kt + 1, cur ^ 1);
      asm volatile("s_waitcnt vmcnt(10)" ::: "memory");  // stage(kt) done; kt+1 in flight
    } else {
      asm volatile("s_waitcnt vmcnt(0)" ::: "memory");
    }
    __builtin_amdgcn_sched_barrier(0);
#pragma unroll
    for (int kk = 0; kk < 2; ++kk) {
      int sw = kk ? sw1 : sw0;
      short8 af[4], bf[6];
#pragma unroll
      for (int i = 0; i < 4; ++i)
        af[i] = *(const short8*)&As[cur][(wm + i * 16 + ln) * 64 + sw];
#pragma unroll
      for (int g = 0; g < 6; ++g)
        bf[g] = *(const short8*)&Bs[cur][(wn2 + g * 16 + ln) * 64 + sw];
#pragma unroll
      for (int g = 0; g < 6; ++g)
#pragma unroll
        for (int i = 0; i < 4; ++i)
          acc[i][g] = __builtin_amdgcn_mfma_f32_16x16x32_bf16(af[i], bf[g], acc[i][g], 0, 0, 0);
    }
    cur ^= 1;
  }

  // ---- epilogue v26 ----
  // wave-col 0: full head0 (groups 0-3) + head1 d0-31 (groups 4,5)
  // wave-col 1: head1 d32-63 (groups 0,1) + full head2 (groups 2-5)
  // straddle exchange via As (exactly 32 KB): [wr][wc][g2][mi][lane] f32x4
  __syncthreads();
  f32x4* xch = (f32x4*)(&As[0][0]);
  {
    int xbase = ((wr * 2 + wc) * 2) * 4 * 64;
#pragma unroll
    for (int g2 = 0; g2 < 2; ++g2)
#pragma unroll
      for (int mi = 0; mi < 4; ++mi)
        xch[xbase + (g2 * 4 + mi) * 64 + lane] = acc[mi][wc ? g2 : 4 + g2];
  }
  __syncthreads();
  f32x4 part[2][4];
  {
    int pbase = ((wr * 2 + (wc ^ 1)) * 2) * 4 * 64;
#pragma unroll
    for (int g2 = 0; g2 < 2; ++g2)
#pragma unroll
      for (int mi = 0; mi < 4; ++mi)
        part[g2][mi] = xch[pbase + (g2 * 4 + mi) * 64 + lane];
  }

  // ---- full head (head0 for col0, head2 for col1) ----
  {
    int hh = wc ? 2 : 0;
    int gb = wc ? 2 : 0;
    int gc0 = n0 + hh * 64;
    int sec = gc0 >> 10, h = (gc0 & 1023) >> 6;
    if (sec < 2) {
      u16* Out = (sec == 0) ? Qo : Ko;
      float sc = (sec == 0) ? 0.180336880f : 1.0f;   // 0.125 * log2(e)
#pragma unroll
      for (int mi = 0; mi < 4; ++mi)
#pragma unroll
        for (int j = 0; j < 4; ++j) {
          int mm = m0 + wm + mi * 16 + kg * 4 + j;
          int l = mm & (L_ - 1), bb = mm >> 11;
          const float2* tl = rope + l * 32;
          size_t base = ((size_t)(bb * H_ + h) * L_ + l) * D_;
#pragma unroll
          for (int g2 = 0; g2 < 2; ++g2) {
            int dA = g2 * 16 + ln;
            float xa = acc[mi][gb + g2][j], xb = acc[mi][gb + g2 + 2][j];
            float2 fA = tl[dA >> 1];
            float2 fB = tl[16 + (dA >> 1)];
            Out[base + dA] = f2bf((fA.x * xa - fA.y * xb) * sc);
            Out[base + dA + 32] = f2bf((fB.x * xb + fB.y * xa) * sc);
          }
        }
    } else {
      // V full head -> chunk-tiled + kv-permuted
#pragma unroll
      for (int mi = 0; mi < 4; ++mi)
#pragma unroll
        for (int j = 0; j < 4; ++j) {
          int mm = m0 + wm + mi * 16 + kg * 4 + j;
          int l = mm & (L_ - 1), bb = mm >> 11;
          int m = l & 31;
          int sp = ((m >> 2) & 3) * 8 + ((m >> 4) & 1) * 4 + (m & 3);
          size_t base = (size_t)(bb * H_ + h) * (L_ * D_) + (size_t)(l >> 5) * 2048 + sp;
#pragma unroll
          for (int g2 = 0; g2 < 4; ++g2) {
            int d = g2 * 16 + ln;
            Vo[base + (size_t)d * 32] = f2bf(acc[mi][gb + g2][j]);
          }
        }
    }
  }

  // ---- straddle head (hh=1): col0 owns d0-31 (xa), col1 owns d32-63 (xb) ----
  {
    int gc0 = n0 + 64;
    int sec = gc0 >> 10, h = (gc0 & 1023) >> 6;
    if (sec < 2) {
      u16* Out = (sec == 0) ? Qo : Ko;
      float sc = (sec == 0) ? 0.180336880f : 1.0f;
#pragma unroll
      for (int mi = 0; mi < 4; ++mi)
#pragma unroll
        for (int j = 0; j < 4; ++j) {
          int mm = m0 + wm + mi * 16 + kg * 4 + j;
          int l = mm & (L_ - 1), bb = mm >> 11;
          const float2* tl = rope + l * 32;
          size_t base = ((size_t)(bb * H_ + h) * L_ + l) * D_;
#pragma unroll
          for (int g2 = 0; g2 < 2; ++g2) {
            int dA = g2 * 16 + ln;
            float2 fA = tl[dA >> 1];
            float2 fB = tl[16 + (dA >> 1)];
            if (wc == 0) {
              float xa = acc[mi][4 + g2][j], xb = part[g2][mi][j];
              Out[base + dA] = f2bf((fA.x * xa - fA.y * xb) * sc);
            } else {
              float xb = acc[mi][g2][j], xa = part[g2][mi][j];
              Out[base + dA + 32] = f2bf((fB.x * xb + fB.y * xa) * sc);
            }
          }
        }
    } else {
      // V straddle: direct store (no pairing needed)
#pragma unroll
      for (int mi = 0; mi < 4; ++mi)
#pragma unroll
        for (int j = 0; j < 4; ++j) {
          int mm = m0 + wm + mi * 16 + kg * 4 + j;
          int l = mm & (L_ - 1), bb = mm >> 11;
          int m = l & 31;
          int sp = ((m >> 2) & 3) * 8 + ((m >> 4) & 1) * 4 + (m & 3);
          size_t base = (size_t)(bb * H_ + h) * (L_ * D_) + (size_t)(l >> 5) * 2048 + sp;
#pragma unroll
          for (int g2 = 0; g2 < 2; ++g2) {
            int d = (wc ? 32 : 0) + g2 * 16 + ln;
            Vo[base + (size_t)d * 32] = f2bf(acc[mi][wc ? g2 : 4 + g2][j]);
          }
        }
    }
  }
}

// ---------------- out-projection GEMM v24: BK=64 counted pipeline ----------------

__global__ __launch_bounds__(256) void oproj_k(
    const u16* __restrict__ A, const u16* __restrict__ Bt, float* __restrict__ Out)
{
  const int K = 1024;
  __shared__ alignas(16) u16 As[2][4096];   // 64 x 64
  __shared__ alignas(16) u16 Bs[2][8192];   // 128 x 64
  int tid = threadIdx.x;
  int orig = blockIdx.x;               // 0..511
  int xcd = orig & 7, idx = orig >> 3; // 0..63
  int px = xcd & 1, py = xcd >> 1;
  int tn = px * 4 + (idx & 3);         // 0..7
  int tm = py * 16 + (idx >> 2);       // 0..63
  int m0 = tm * 64, n0 = tn * 128;
  int prow = tid >> 3;
  int pB = (tid & 7) ^ (prow & 7);
  const u16* gA0 = A + (size_t)(m0 + prow) * K + pB * 8;
  const u16* gB0 = Bt + (size_t)(n0 + prow) * K + pB * 8;
  int wid = tid >> 6, lane = tid & 63, ln = lane & 15, kg = lane >> 4;
  int wm = (wid >> 1) * 32, wn = (wid & 1) * 64;
  f32x4 acc[2][4] = {};
  int sw0 = (kg ^ (ln & 7)) * 8;
  int sw1 = ((4 + kg) ^ (ln & 7)) * 8;

  auto stage = [&](int kt, int buf) {
#pragma unroll
    for (int s = 0; s < 2; ++s)
      gl16(gA0 + (size_t)s * 32 * K + kt * 64, &As[buf][s * 2048 + tid * 8]);
#pragma unroll
    for (int s = 0; s < 4; ++s)
      gl16(gB0 + (size_t)s * 32 * K + kt * 64, &Bs[buf][s * 2048 + tid * 8]);
  };

  stage(0, 0);
  int cur = 0;
  for (int kt = 0; kt < 16; ++kt) {
    __builtin_amdgcn_s_barrier();
    if (kt + 1 < 16) {
      stage(kt + 1, cur ^ 1);
      asm volatile("s_waitcnt vmcnt(6)" ::: "memory");   // stage(kt) done; kt+1 in flight
    } else {
      asm volatile("s_waitcnt vmcnt(0)" ::: "memory");
    }
    __builtin_amdgcn_sched_barrier(0);
#pragma unroll
    for (int kk = 0; kk < 2; ++kk) {
      int sw = kk ? sw1 : sw0;
      short8 af[2], bfr[4];
#pragma unroll
      for (int i = 0; i < 2; ++i) af[i] = *(const short8*)&As[cur][(wm + i * 16 + ln) * 64 + sw];
#pragma unroll
      for (int i = 0; i < 4; ++i) bfr[i] = *(const short8*)&Bs[cur][(wn + i * 16 + ln) * 64 + sw];
#pragma unroll
      for (int mi = 0; mi < 2; ++mi)
#pragma unroll
        for (int ni = 0; ni < 4; ++ni)
          acc[mi][ni] = __builtin_amdgcn_mfma_f32_16x16x32_bf16(af[mi], bfr[ni], acc[mi][ni], 0, 0, 0);
    }
    cur ^= 1;
  }
#pragma unroll
  for (int mi = 0; mi < 2; ++mi)
#pragma unroll
    for (int j = 0; j < 4; ++j) {
      int mm = m0 + wm + mi * 16 + kg * 4 + j;
#pragma unroll
      for (int ni = 0; ni < 4; ++ni)
        Out[(size_t)mm * 1024 + n0 + wn + ni * 16 + ln] = acc[mi][ni][j];
    }
}

// ---------------- flash attention v25: v20 structure + zero-shuffle PV ----------------
__global__ __launch_bounds__(256) void attn_k(
    const u16* __restrict__ Q, const u16* __restrict__ K,
    const u16* __restrict__ V, u16* __restrict__ AO)
{
  __shared__ alignas(16) u16 Ks[2][8192];
  __shared__ alignas(16) u16 Vs[2][8192];
  int tid = threadIdx.x;
  int wid = tid >> 6, lane = tid & 63;
  int ln = lane & 15, kg = lane >> 4;
  int orig = blockIdx.x;               // 0..511
  int swz = (orig & 7) * 64 + (orig >> 3);   // bijective (512 % 8 == 0)
  int bh = swz >> 4;
  int i = swz & 15;
  int tA = i, tB = 31 - i;
  int nA = (tA >> 1) + 1;              // 128-kv chunks for tile A
  int nB = (tB >> 1) + 1;
  const int NCH = 17;                  // nA + nB = 17 for every i
  int q0A = tA * 64 + wid * 16;
  int q0B = tB * 64 + wid * 16;
  const u16* Qh = Q + (size_t)bh * L_ * D_;
  const u16* Kh = K + (size_t)bh * L_ * D_;
  const u16* Vt = V + (size_t)bh * L_ * D_;   // chunk-tiled [l/32][64][32], kv-permuted

  // staging sources (256 threads; K and V pre-swizzled source, linear LDS dest)
  int srow = tid >> 3, sblk = tid & 7;
  const u16* kb = Kh + (size_t)srow * 64 + ((sblk ^ (srow & 7)) << 3);
  const u16* vb = Vt + (size_t)(tid >> 2) * 32 + (((tid & 3) ^ ((tid >> 3) & 3)) << 3);

  short8 qfA0 = *(const short8*)(Qh + (size_t)(q0A + ln) * D_ + kg * 8);
  short8 qfA1 = *(const short8*)(Qh + (size_t)(q0A + ln) * D_ + 32 + kg * 8);
  short8 qfB0 = *(const short8*)(Qh + (size_t)(q0B + ln) * D_ + kg * 8);
  short8 qfB1 = *(const short8*)(Qh + (size_t)(q0B + ln) * D_ + 32 + kg * 8);

  f32x4 oA[4] = {}, oB[4] = {};
  float lsA = 0.f, lsB = 0.f;
  int sw0 = (kg ^ (ln & 7)) * 8;
  int sw1 = ((4 + kg) ^ (ln & 7)) * 8;
  int vsw = (kg ^ ((ln >> 1) & 3)) * 8;   // V read block swizzle
  int jdA = (tA & 1) * 4 + wid;        // diag sub-tile in tile A's last chunk
  int jdB = (tB & 1) * 4 + wid;

  auto stage = [&](int chunk, int buf) {
    const u16* kc = kb + (size_t)chunk * 8192;
    const u16* vc = vb + (size_t)chunk * 8192;
#pragma unroll
    for (int s2 = 0; s2 < 4; ++s2) {
      gl16(kc + s2 * 2048, &Ks[buf][s2 * 2048 + tid * 8]);
      gl16(vc + s2 * 2048, &Vs[buf][s2 * 2048 + tid * 8]);
    }
  };
  auto seq = [&](int c) { return (c < nA) ? c : c - nA; };

  // one 128-kv chunk step for one 16-q tile. jd: 0..7 = diagonal sub-tile
  // (mask j>jd fully, j==jd elementwise); 8 = no masking.
  auto step = [&](int cur, int jd, short8 qf0, short8 qf1,
                  float& lsum, f32x4 (&o)[4]) {
    f32x4 s[8];
    __builtin_amdgcn_s_setprio(1);
#pragma unroll
    for (int j = 0; j < 8; ++j) {
      short8 ka = *(const short8*)&Ks[cur][(j * 16 + ln) * 64 + sw0];
      short8 kc = *(const short8*)&Ks[cur][(j * 16 + ln) * 64 + sw1];
      f32x4 t = {};
      t = __builtin_amdgcn_mfma_f32_16x16x32_bf16(ka, qf0, t, 0, 0, 0);
      t = __builtin_amdgcn_mfma_f32_16x16x32_bf16(kc, qf1, t, 0, 0, 0);
      s[j] = t;
    }
    __builtin_amdgcn_s_setprio(0);
    if (jd < 8) {                      // wave-uniform branch
#pragma unroll
      for (int j = 0; j < 8; ++j)
#pragma unroll
        for (int r = 0; r < 4; ++r) {
          bool kill = (j > jd) | ((j == jd) & ((kg * 4 + r) > ln));
          if (kill) s[j][r] = -1e30f;
        }
    }
    float ps = 0.f;
    u32 wA[8], wB[8];
#pragma unroll
    for (int j = 0; j < 8; ++j) {
      float p0, p1, p2, p3;
      asm("v_exp_f32 %0, %1" : "=v"(p0) : "v"(s[j][0]));
      asm("v_exp_f32 %0, %1" : "=v"(p1) : "v"(s[j][1]));
      asm("v_exp_f32 %0, %1" : "=v"(p2) : "v"(s[j][2]));
      asm("v_exp_f32 %0, %1" : "=v"(p3) : "v"(s[j][3]));
      ps += (p0 + p1) + (p2 + p3);
      asm("v_cvt_pk_bf16_f32 %0, %1, %2" : "=v"(wA[j]) : "v"(p0), "v"(p1));
      asm("v_cvt_pk_bf16_f32 %0, %1, %2" : "=v"(wB[j]) : "v"(p2), "v"(p3));
    }
    lsum += ps;
#pragma unroll
    for (int g = 0; g < 4; ++g) {
      // zero-shuffle PV: V slot order matches native P distribution
      union { u32 u[4]; short8 s8; } pu;
      pu.u[0] = wA[2 * g];
      pu.u[1] = wB[2 * g];
      pu.u[2] = wA[2 * g + 1];
      pu.u[3] = wB[2 * g + 1];
      short8 vf0 = *(const short8*)&Vs[cur][g * 2048 + ln * 32 + vsw];
      short8 vf1 = *(const short8*)&Vs[cur][g * 2048 + (16 + ln) * 32 + vsw];
      short8 vf2 = *(const short8*)&Vs[cur][g * 2048 + (32 + ln) * 32 + vsw];
      short8 vf3 = *(const short8*)&Vs[cur][g * 2048 + (48 + ln) * 32 + vsw];
      __builtin_amdgcn_s_setprio(1);
      o[0] = __builtin_amdgcn_mfma_f32_16x16x32_bf16(vf0, pu.s8, o[0], 0, 0, 0);
      o[1] = __builtin_amdgcn_mfma_f32_16x16x32_bf16(vf1, pu.s8, o[1], 0, 0, 0);
      o[2] = __builtin_amdgcn_mfma_f32_16x16x32_bf16(vf2, pu.s8, o[2], 0, 0, 0);
      o[3] = __builtin_amdgcn_mfma_f32_16x16x32_bf16(vf3, pu.s8, o[3], 0, 0, 0);
      __builtin_amdgcn_s_setprio(0);
    }
  };

  stage(seq(0), 0);
  int cur = 0;

  for (int c = 0; c < NCH; ++c) {
    __builtin_amdgcn_s_barrier();
    if (c + 1 < NCH) {
      stage(seq(c + 1), cur ^ 1);
      asm volatile("s_waitcnt vmcnt(8)" ::: "memory");   // stage(c) done; c+1 in flight
    } else {
      asm volatile("s_waitcnt vmcnt(0)" ::: "memory");
    }
    __builtin_amdgcn_sched_barrier(0);

    if (c < nA) {
      step(cur, (c == nA - 1) ? jdA : 8, qfA0, qfA1, lsA, oA);
    } else {
      int cl = c - nA;
      step(cur, (cl == nB - 1) ? jdB : 8, qfB0, qfB1, lsB, oB);
    }
    cur ^= 1;
  }

  // ---- final l reduction + store, both tiles ----
  int b = bh >> 4, h = bh & 15;
  lsA += __shfl_xor(lsA, 16);
  lsA += __shfl_xor(lsA, 32);
  lsB += __shfl_xor(lsB, 16);
  lsB += __shfl_xor(lsB, 32);
  float invA = 1.0f / lsA, invB = 1.0f / lsB;
  u16* rowA = AO + ((size_t)(b * L_ + q0A + ln) * H_ + h) * D_;
  u16* rowB = AO + ((size_t)(b * L_ + q0B + ln) * H_ + h) * D_;
#pragma unroll
  for (int dt = 0; dt < 4; ++dt) {
    union { u16 pk[4]; uint2 v; } uA, uB;
#pragma unroll
    for (int r = 0; r < 4; ++r) {
      uA.pk[r] = f2bf(oA[dt][r] * invA);
      uB.pk[r] = f2bf(oB[dt][r] * invB);
    }
    *(uint2*)(rowA + dt * 16 + kg * 4) = uA.v;
    *(uint2*)(rowB + dt * 16 + kg * 4) = uB.v;
  }
}

// ---------------- launch ----------------

extern "C" void kernel_launch(void* const* d_in, const int* in_sizes, int n_in,
                              void* d_out, int out_size, void* d_ws, size_t ws_size,
                              hipStream_t stream) {
  (void)in_sizes; (void)n_in; (void)out_size; (void)ws_size;
  const float* x   = (const float*)d_in[0];
  const int*   pos = (const int*)d_in[1];
  // d_in[2] = additive causal mask (we apply causal masking directly)
  const float* Wq  = (const float*)d_in[3];
  const float* Wk  = (const float*)d_in[4];
  const float* Wv  = (const float*)d_in[5];
  const float* Wo  = (const float*)d_in[6];

  char* ws = (char*)d_ws;
  u16* xbf = (u16*)ws;                        // 8 MB
  u16* Wt3 = (u16*)(ws + (size_t)( 8 << 20)); // 6 MB ([Wq|Wk|Wv]^T stacked)
  u16* Wto = (u16*)(ws + (size_t)(14 << 20)); // 2 MB
  u16* Qb  = (u16*)(ws + (size_t)(16 << 20)); // 8 MB each
  u16* Kb  = (u16*)(ws + (size_t)(24 << 20));
  u16* Vt  = (u16*)(ws + (size_t)(32 << 20)); // chunk-tiled, kv-permuted
  u16* AO  = (u16*)(ws + (size_t)(40 << 20));
  float2* tab = (float2*)(ws + (size_t)(48 << 20)); // 512 KB

  prep_k<<<6400, 256, 0, stream>>>(
      x, xbf, Wq, Wk, Wv, Wo,
      Wt3, Wt3 + (size_t)1048576, Wt3 + (size_t)2097152, Wto, pos, tab);
  qkv_gemm_k<<<512, 256, 0, stream>>>(xbf, Wt3, Qb, Kb, Vt, tab);
  attn_k<<<512, 256, 0, stream>>>(Qb, Kb, Vt, AO);
  oproj_k<<<512, 256, 0, stream>>>(AO, Wto, (float*)d_out);
}